// Round 8
// baseline (220.309 us; speedup 1.0000x reference)
//
#include <hip/hip_runtime.h>
#include <stdint.h>

// Problem constants (match reference)
#define NP 32    // num networks (P)
#define NH 128   // hidden (H)
#define NB 32    // batch (B)
#define NT 256   // time (T)
#define FH 512   // 4*H

typedef __attribute__((ext_vector_type(4))) float float4_t;
typedef __attribute__((ext_vector_type(8))) __bf16 bf16x8;
typedef __attribute__((ext_vector_type(4))) __bf16 bf16x4;

static __device__ __forceinline__ float4_t mfma_bf16(bf16x8 a, bf16x8 b, float4_t c) {
  return __builtin_amdgcn_mfma_f32_16x16x32_bf16(a, b, c, 0, 0, 0);
}

#define LOG2E 1.4426950408889634f

// Raw workgroup barrier: drains LDS ops only (cross-wave h visibility), does
// NOT drain vmcnt — pending global loads/stores stay in flight across it.
#define BAR() __asm__ volatile("s_waitcnt lgkmcnt(0)\n\ts_barrier" ::: "memory")
#define SB()  __builtin_amdgcn_sched_barrier(0)

// ---------------------------------------------------------------------------
// R16: PER-GATE STREAMING for MFMA<->VALU pipe overlap, on the R15 base.
// R15 post-mortem: 163us = 1533 cyc/step = matrix 776 + VALU/trans ~650 +
// sync ~100, ADDITIVE (MfmaUtil 45 + VALUBusy 43 = 88%). The pipes are
// separate HW (m114: MFMA-wave + VALU-wave co-schedule fully) but our waves
// are homogeneous in phase: all 20 MFMAs, then all activation — during the
// matrix burst no wave has VALU ready and vice versa. Fix: each gate's
// activation depends only on ITS acc, so stream
//   [g0,g1 chains] SB [act i,f] SB [g2,g3 chains] SB [act g,o + tail]
// (sched_barrier(0) pins only 3 boundaries — NOT m141's pin-everything;
// all memory ops stay in segment 0). The 2 waves/SIMD then slip: one
// wave's act-VALU issues under the other's matrix backlog. Target: step ->
// max(matrix 790, valu 650) + sync ~= 950-1150 cyc.
// Also: unroll x2 (rd/wr literal -> LDS offsets fold to immediates); head
// rotated to wave (t&7) — every wave holds identical ah, so round-robin
// spreads the head's 4 MFMAs across SIMDs instead of always SIMD0.
// Overlap signature to check: MfmaUtil + VALUBusy > 105%.
// SESSION RULES: launch_bounds 2nd arg never !=1 (R9-R11 spill death);
// waves_per_eu is the trusted reg-budget knob (R14/R15); no DS ops in loop
// beyond h write/read (R5); co-residency worthless at issue saturation
// (R14); M=4/256 blocks is the per-CU MFMA optimum (R12/R15).
// ---------------------------------------------------------------------------

// Prepass: X f32 -> bf16 into ws (same [B][T][P] layout). 262144 elems.
__global__ __launch_bounds__(512, 1) void xcvt(
    const float* __restrict__ X, __bf16* __restrict__ Xb)
{
  const int i = (blockIdx.x * 512 + threadIdx.x) * 4;
  float4_t v = *(const float4_t*)(X + i);
  bf16x4 o;
#pragma unroll
  for (int j = 0; j < 4; ++j) o[j] = (__bf16)v[j];
  *(bf16x4*)(Xb + i) = o;
}

__global__ __attribute__((amdgpu_flat_work_group_size(512, 512),
                          amdgpu_waves_per_eu(2, 2)))
void clstm_fused4(
    const __bf16* __restrict__ Xb, const float* __restrict__ Wih,
    const float* __restrict__ Whh, const float* __restrict__ bih,
    const float* __restrict__ bhh, const float* __restrict__ Wout,
    const float* __restrict__ bout, float* __restrict__ out)
{
  const int net = blockIdx.x >> 3, bq = blockIdx.x & 7;
  const int tid = threadIdx.x;
  const int w = tid >> 6, lane = tid & 63;
  const int quad = lane >> 4, l16 = lane & 15;

  // h A-fragments, double buffered, 4 DISTINCT rows: [buf][kc][kquad][m<4][j]
  __shared__ __bf16 hfrag[2][4][4][4][8];   // 2 KB total

  { ((int*)hfrag)[tid] = 0; }   // h0 = 0, both buffers
  __syncthreads();

  // ---- load weights into register B-fragments (one-time) ----
  // B-frag layout for 16x16x32: lane holds B[k = quad*8 + j][n = l16].
  bf16x8 bfrag[4][5];
  float4_t bias4[4];
#pragma unroll
  for (int g = 0; g < 4; ++g) {
    const float scale = (g == 2) ? (-2.0f*LOG2E) : (-LOG2E);
    const int col = g*NH + w*16 + l16;
#pragma unroll
    for (int kc = 0; kc < 5; ++kc) {
      const float* src = (kc == 0) ? (Wih + ((size_t)net*FH + col)*NP + quad*8)
                                   : (Whh + ((size_t)net*FH + col)*NH + (kc-1)*32 + quad*8);
      bf16x8 bf;
#pragma unroll
      for (int j = 0; j < 8; ++j) bf[j] = (__bf16)(src[j] * scale);
      bfrag[g][kc] = bf;
    }
    const float b = (bih[net*FH + col] + bhh[net*FH + col]) * scale;
    bias4[g] = (float4_t){b, b, b, b};
  }

  // head B-frags (ALL waves now — head rotates across waves): B[k][n] =
  // wout[k] broadcast over all 16 cols n.
  bf16x8 wof[4];
#pragma unroll
  for (int kc = 0; kc < 4; ++kc) {
    const float* wp = Wout + net*NH + kc*32 + quad*8;
#pragma unroll
    for (int j = 0; j < 8; ++j) wof[kc][j] = (__bf16)wp[j];
  }
  const float bo = bout[net];

  // c state, PRE-SCALED by -2log2e (saves a mul on the h critical chain)
  float cs = 0.f;
  const float S2 = -2.0f*LOG2E;

  // x source (bf16 prepass, layout == X): batch bq*4 + (l16&3) (4x dup)
  int xoff = (bq*4 + (l16 & 3))*(NT*NP) + quad*8;

  // h write coords for unit u = w*16 + l16; row = quad (this lane's batch)
  const int kcp = w >> 1, q2 = ((w & 1) << 1) | (l16 >> 3), jj = l16 & 7;

  // head store base: out[(bq*4 + r)*NT*NP + t*NP + net]
  float* outp = out + ((size_t)bq*4)*(NT*NP) + net;

  // preload ax for t=0
  bf16x8 ax = *(const bf16x8*)(Xb + xoff);
  xoff += NP;

// ---- one recurrence step; RD/WR are LITERALS (unroll x2) ----
#define STEP(RD, WR, T_)                                                      \
  do {                                                                        \
    /* seg 0: ds_reads, x-MFMAs (chain roots, C=bias), x prefetch, g0/g1 */   \
    bf16x8 ah0 = *(const bf16x8*)&hfrag[RD][0][quad][l16 & 3][0];             \
    bf16x8 ah1 = *(const bf16x8*)&hfrag[RD][1][quad][l16 & 3][0];             \
    bf16x8 ah2 = *(const bf16x8*)&hfrag[RD][2][quad][l16 & 3][0];             \
    bf16x8 ah3 = *(const bf16x8*)&hfrag[RD][3][quad][l16 & 3][0];             \
    float4_t a0 = mfma_bf16(ax, bfrag[0][0], bias4[0]);                       \
    float4_t a1 = mfma_bf16(ax, bfrag[1][0], bias4[1]);                       \
    float4_t a2 = mfma_bf16(ax, bfrag[2][0], bias4[2]);                       \
    float4_t a3 = mfma_bf16(ax, bfrag[3][0], bias4[3]);                       \
    if ((T_) + 1 < NT) ax = *(const bf16x8*)(Xb + xoff);                      \
    xoff += NP;                                                               \
    a0 = mfma_bf16(ah0, bfrag[0][1], a0);                                     \
    a1 = mfma_bf16(ah0, bfrag[1][1], a1);                                     \
    a0 = mfma_bf16(ah1, bfrag[0][2], a0);                                     \
    a1 = mfma_bf16(ah1, bfrag[1][2], a1);                                     \
    a0 = mfma_bf16(ah2, bfrag[0][3], a0);                                     \
    a1 = mfma_bf16(ah2, bfrag[1][3], a1);                                     \
    a0 = mfma_bf16(ah3, bfrag[0][4], a0);                                     \
    a1 = mfma_bf16(ah3, bfrag[1][4], a1);                                     \
    SB();                                                                     \
    /* seg 1: act for i,f — overlaps the other wave's matrix backlog */      \
    float gi = (quad & 2) ? ((quad & 1) ? a0[3] : a0[2])                      \
                          : ((quad & 1) ? a0[1] : a0[0]);                     \
    float gf = (quad & 2) ? ((quad & 1) ? a1[3] : a1[2])                      \
                          : ((quad & 1) ? a1[1] : a1[0]);                     \
    float ei = __builtin_amdgcn_exp2f(gi);                                    \
    float ig = __builtin_amdgcn_rcpf(1.0f + ei);                              \
    float ef = __builtin_amdgcn_exp2f(gf);                                    \
    float fg = __builtin_amdgcn_rcpf(1.0f + ef);                              \
    SB();                                                                     \
    /* seg 2: g2/g3 chains */                                                 \
    a2 = mfma_bf16(ah0, bfrag[2][1], a2);                                     \
    a3 = mfma_bf16(ah0, bfrag[3][1], a3);                                     \
    a2 = mfma_bf16(ah1, bfrag[2][2], a2);                                     \
    a3 = mfma_bf16(ah1, bfrag[3][2], a3);                                     \
    a2 = mfma_bf16(ah2, bfrag[2][3], a2);                                     \
    a3 = mfma_bf16(ah2, bfrag[3][3], a3);                                     \
    a2 = mfma_bf16(ah3, bfrag[2][4], a2);                                     \
    a3 = mfma_bf16(ah3, bfrag[3][4], a3);                                     \
    SB();                                                                     \
    /* seg 3: act g,o + state + write + rotating head */                      \
    float gg = (quad & 2) ? ((quad & 1) ? a2[3] : a2[2])                      \
                          : ((quad & 1) ? a2[1] : a2[0]);                     \
    float go = (quad & 2) ? ((quad & 1) ? a3[3] : a3[2])                      \
                          : ((quad & 1) ? a3[1] : a3[0]);                     \
    float eg = __builtin_amdgcn_exp2f(fminf(gg, 126.0f));                     \
    float rg = __builtin_amdgcn_rcpf(1.0f + eg);                              \
    float t0 = S2 * rg;                                                       \
    float gg2 = t0 - t0 * eg;                        /* tanh(g)*S2 */         \
    float eo = __builtin_amdgcn_exp2f(go);                                    \
    float og = __builtin_amdgcn_rcpf(1.0f + eo);                              \
    cs = fg * cs + ig * gg2;                         /* c * S2 */             \
    float ec = __builtin_amdgcn_exp2f(fminf(cs, 126.0f));                     \
    float rc = __builtin_amdgcn_rcpf(1.0f + ec);                              \
    float h_ = og * (rc - ec * rc);                  /* o * tanh(c) */        \
    hfrag[WR][kcp][q2][quad][jj] = (__bf16)h_;                                \
    if ((T_) > 0 && w == ((T_) & 7)) {                                        \
      float4_t p0 = {bo, bo, bo, bo};                                         \
      float4_t p1 = {0.f, 0.f, 0.f, 0.f};                                     \
      p0 = mfma_bf16(ah0, wof[0], p0);                                        \
      p1 = mfma_bf16(ah2, wof[2], p1);                                        \
      p0 = mfma_bf16(ah1, wof[1], p0);                                        \
      p1 = mfma_bf16(ah3, wof[3], p1);                                        \
      float4_t po = p0 + p1;                                                  \
      if (lane == 0) {                                                        \
        _Pragma("unroll")                                                     \
        for (int r = 0; r < 4; ++r)                                           \
          outp[(size_t)r*(NT*NP) + ((T_) - 1)*NP] = po[r];                    \
      }                                                                       \
    }                                                                         \
    BAR();                                                                    \
  } while (0)

  for (int t = 0; t < NT; t += 2) {
    STEP(0, 1, t);
    STEP(1, 0, t + 1);
  }
#undef STEP

  // ---- epilogue: head for t = NT-1 (h_{NT-1} is in hfrag[NT&1]) ----
  if (w == 0) {
    bf16x8 ahf[4];
#pragma unroll
    for (int kc = 0; kc < 4; ++kc)
      ahf[kc] = *(const bf16x8*)&hfrag[NT & 1][kc][quad][l16 & 3][0];
    float4_t p0 = {bo, bo, bo, bo};
    float4_t p1 = {0.f, 0.f, 0.f, 0.f};
    p0 = mfma_bf16(ahf[0], wof[0], p0);
    p1 = mfma_bf16(ahf[2], wof[2], p1);
    p0 = mfma_bf16(ahf[1], wof[1], p0);
    p1 = mfma_bf16(ahf[3], wof[3], p1);
    float4_t po = p0 + p1;
    if (lane == 0) {
#pragma unroll
      for (int r = 0; r < 4; ++r)
        outp[(size_t)r*(NT*NP) + (NT - 1)*NP] = po[r];
    }
  }
}

// ---------------------------------------------------------------------------
// Fallback (ws too small): R8 kernel verbatim — M=4 / 256 blocks, fused
// head, f32 X loads, 219us rocprof. No workspace use.
// ---------------------------------------------------------------------------
__global__ __launch_bounds__(512, 1) void clstm_fused_fb(
    const float* __restrict__ X, const float* __restrict__ Wih,
    const float* __restrict__ Whh, const float* __restrict__ bih,
    const float* __restrict__ bhh, const float* __restrict__ Wout,
    const float* __restrict__ bout, float* __restrict__ out)
{
  const int net = blockIdx.x >> 3, bq = blockIdx.x & 7;
  const int tid = threadIdx.x;
  const int w = tid >> 6, lane = tid & 63;
  const int quad = lane >> 4, l16 = lane & 15;

  __shared__ __bf16 hfrag[2][4][4][4][8];
  { ((int*)hfrag)[tid] = 0; }
  __syncthreads();

  bf16x8 bfrag[4][5];
  float4_t bias4[4];
#pragma unroll
  for (int g = 0; g < 4; ++g) {
    const float scale = (g == 2) ? (-2.0f*LOG2E) : (-LOG2E);
    const int col = g*NH + w*16 + l16;
#pragma unroll
    for (int kc = 0; kc < 5; ++kc) {
      const float* src = (kc == 0) ? (Wih + ((size_t)net*FH + col)*NP + quad*8)
                                   : (Whh + ((size_t)net*FH + col)*NH + (kc-1)*32 + quad*8);
      bf16x8 bf;
#pragma unroll
      for (int j = 0; j < 8; ++j) bf[j] = (__bf16)(src[j] * scale);
      bfrag[g][kc] = bf;
    }
    const float b = (bih[net*FH + col] + bhh[net*FH + col]) * scale;
    bias4[g] = (float4_t){b, b, b, b};
  }

  bf16x8 wof[4];
#pragma unroll
  for (int kc = 0; kc < 4; ++kc) {
    const float* wp = Wout + net*NH + kc*32 + quad*8;
#pragma unroll
    for (int j = 0; j < 8; ++j) wof[kc][j] = (__bf16)wp[j];
  }
  const float bo = bout[net];

  float cs = 0.f;
  const float S2 = -2.0f*LOG2E;

  const float* xrow = X + (size_t)(bq*4 + (l16 & 3))*(NT*NP) + quad*8;
  const int kcp = w >> 1, q2 = ((w & 1) << 1) | (l16 >> 3), jj = l16 & 7;
  float* outp = out + ((size_t)bq*4)*(NT*NP) + net;

  bf16x8 ax;
  {
    float xv0[8];
    *(float4_t*)&xv0[0] = *(const float4_t*)xrow;
    *(float4_t*)&xv0[4] = *(const float4_t*)(xrow + 4);
#pragma unroll
    for (int j = 0; j < 8; ++j) ax[j] = (__bf16)xv0[j];
  }
  const float* xp = xrow + NP;
  float xv[8] = {0.f,0.f,0.f,0.f,0.f,0.f,0.f,0.f};

  for (int t = 0; t < NT; ++t) {
    const int rd = t & 1, wr = rd ^ 1;
    bf16x8 ah[4];
#pragma unroll
    for (int kc = 0; kc < 4; ++kc)
      ah[kc] = *(const bf16x8*)&hfrag[rd][kc][quad][l16 & 3][0];
    float4_t accx[4];
#pragma unroll
    for (int g = 0; g < 4; ++g)
      accx[g] = mfma_bf16(ax, bfrag[g][0], bias4[g]);
    if (t + 1 < NT) {
      *(float4_t*)&xv[0] = *(const float4_t*)xp;
      *(float4_t*)&xv[4] = *(const float4_t*)(xp + 4);
    }
    float4_t acc[4];
#pragma unroll
    for (int g = 0; g < 4; ++g) {
      float4_t a0 = mfma_bf16(ah[0], bfrag[g][1], accx[g]);
      float4_t a1 = mfma_bf16(ah[2], bfrag[g][3], (float4_t){0.f,0.f,0.f,0.f});
      a0 = mfma_bf16(ah[1], bfrag[g][2], a0);
      a1 = mfma_bf16(ah[3], bfrag[g][4], a1);
      acc[g] = a0 + a1;
    }
    float gv[4];
#pragma unroll
    for (int g = 0; g < 4; ++g) {
      float a01 = (quad & 1) ? acc[g][1] : acc[g][0];
      float a23 = (quad & 1) ? acc[g][3] : acc[g][2];
      gv[g] = (quad & 2) ? a23 : a01;
    }
    float h;
    {
      float ei = __builtin_amdgcn_exp2f(gv[0]);
      float ig = __builtin_amdgcn_rcpf(1.0f + ei);
      float ef = __builtin_amdgcn_exp2f(gv[1]);
      float fg = __builtin_amdgcn_rcpf(1.0f + ef);
      float eg = __builtin_amdgcn_exp2f(fminf(gv[2], 126.0f));
      float rg = __builtin_amdgcn_rcpf(1.0f + eg);
      float t0 = S2 * rg;
      float gg2 = t0 - t0 * eg;
      float eo = __builtin_amdgcn_exp2f(gv[3]);
      float og = __builtin_amdgcn_rcpf(1.0f + eo);
      cs = fg * cs + ig * gg2;
      float ec = __builtin_amdgcn_exp2f(fminf(cs, 126.0f));
      float rc = __builtin_amdgcn_rcpf(1.0f + ec);
      float th = rc - ec * rc;
      h = og * th;
    }
    hfrag[wr][kcp][q2][quad][jj] = (__bf16)h;
    if (w == 0 && t > 0) {
      float4_t p0 = {bo, bo, bo, bo};
      float4_t p1 = {0.f, 0.f, 0.f, 0.f};
      p0 = mfma_bf16(ah[0], wof[0], p0);
      p1 = mfma_bf16(ah[2], wof[2], p1);
      p0 = mfma_bf16(ah[1], wof[1], p0);
      p1 = mfma_bf16(ah[3], wof[3], p1);
      float4_t po = p0 + p1;
      if (lane == 0) {
#pragma unroll
        for (int r = 0; r < 4; ++r)
          outp[(size_t)r*(NT*NP) + (t - 1)*NP] = po[r];
      }
    }
#pragma unroll
    for (int j = 0; j < 8; ++j) ax[j] = (__bf16)xv[j];
    xp += NP;
    BAR();
  }

  if (w == 0) {
    bf16x8 ahf[4];
#pragma unroll
    for (int kc = 0; kc < 4; ++kc)
      ahf[kc] = *(const bf16x8*)&hfrag[NT & 1][kc][quad][l16 & 3][0];
    float4_t p0 = {bo, bo, bo, bo};
    float4_t p1 = {0.f, 0.f, 0.f, 0.f};
    p0 = mfma_bf16(ahf[0], wof[0], p0);
    p1 = mfma_bf16(ahf[2], wof[2], p1);
    p0 = mfma_bf16(ahf[1], wof[1], p0);
    p1 = mfma_bf16(ahf[3], wof[3], p1);
    float4_t po = p0 + p1;
    if (lane == 0) {
#pragma unroll
      for (int r = 0; r < 4; ++r)
        outp[(size_t)r*(NT*NP) + (NT - 1)*NP] = po[r];
    }
  }
}

extern "C" void kernel_launch(void* const* d_in, const int* in_sizes, int n_in,
                              void* d_out, int out_size, void* d_ws, size_t ws_size,
                              hipStream_t stream) {
  const float* X    = (const float*)d_in[0];
  const float* Wih  = (const float*)d_in[1];
  const float* Whh  = (const float*)d_in[2];
  const float* bih  = (const float*)d_in[3];
  const float* bhh  = (const float*)d_in[4];
  const float* Wout = (const float*)d_in[5];
  const float* bout = (const float*)d_in[6];
  float* out = (float*)d_out;
  (void)in_sizes; (void)n_in; (void)out_size;

  // ws layout: [0, 512KB) X as bf16.
  const size_t need = (size_t)NB*NT*NP*2;
  if (d_ws != nullptr && ws_size >= need) {
    __bf16* wsX = (__bf16*)d_ws;
    xcvt<<<128, 512, 0, stream>>>(X, wsX);
    // 256 blocks = 32 nets x 8 batch-groups (M=4); 1 block/CU; 256-reg
    // budget via waves_per_eu(2,2).
    clstm_fused4<<<256, 512, 0, stream>>>(wsX, Wih, Whh, bih, bhh, Wout,
                                          bout, out);
  } else {
    // R8 fallback: no workspace required.
    clstm_fused_fb<<<256, 512, 0, stream>>>(X, Wih, Whh, bih, bhh, Wout,
                                            bout, out);
  }
}